// Round 4
// baseline (323.985 us; speedup 1.0000x reference)
//
#include <hip/hip_runtime.h>

// ---------------------------------------------------------------------------
// GridNet fused forward: MLP (bf16 MFMA) + softmax + 5x5 gather + sigmoid
// B=262144, GS=(1024,2048), NS=5, layers 2-64-256-512-256-64-75
// R5: 32x32x16 for L3/L4. 253us, MfmaUtil 27.8, no pipe >35%.
// R7: 3 blk/CU (more waves) -> 262us, MfmaUtil 26.7. Occupancy is NOT the
//     lever. Model: per k-iter a wave does MT*NT MFMAs (~17cyc R5) then waits
//     ~200cyc on depth-1 L2 A-load; duty*waves/SIMD == measured MfmaUtil.
// R8: attack per-iter ILP + prefetch depth directly:
//     - M=128 pts/block (512 thr, 2048 blocks): 32-shape MT=2,NT=2 ->
//       4 MFMA/k-iter (~34cyc); per-point weight L2 traffic halves.
//     - rolling depth-4 prefetch (compile-time indexed bufs, full unroll):
//       loads lead consumption by ~136cyc instead of ~34.
//     - launch_bounds(512,2): reg cap 256 (R7 cap 85 strangled scheduling).
//     LDS 154624 B -> 1 block/CU (8 waves); R7 proved blocks/CU isn't the lever.
// ---------------------------------------------------------------------------

#define PI_F     3.14159265358979323846f
#define TWO_PI_F 6.28318530717958647692f

typedef __attribute__((ext_vector_type(8))) short bf16x8;   // 8 bf16 = 4 VGPRs
typedef __attribute__((ext_vector_type(4))) short bf16x4;   // 8 B packed
typedef __attribute__((ext_vector_type(4))) float f32x4;    // 16x16 MFMA C/D
typedef __attribute__((ext_vector_type(16))) float f32x16;  // 32x32 MFMA C/D

__device__ __forceinline__ short f2bf(float f) {
    unsigned u = __builtin_bit_cast(unsigned, f);
    u += 0x7fffu + ((u >> 16) & 1u);            // round-nearest-even
    return (short)(u >> 16);
}

// ws layout (shorts). Weights fragment-packed for MFMA A-operand.
// 16-shape layers (L2,L5,L6): frag f = ot*KT + kt (ot 16-wide, kt 32-deep):
//   lane*8+e <-> W[k = kt*32 + (lane>>4)*8 + e][n = ot*16 + (lane&15)]
// 32-shape layers (L3,L4):    frag f = ot*KT + kt (ot 32-wide, kt 16-deep):
//   lane*8+e <-> W[k = kt*16 + (lane>>5)*8 + e][n = ot*32 + (lane&31)]
// L2: 64x256 (KT=2,  16-shape) @ 0       (16384)
// L3: 256x512(KT=16, 32-shape) @ 16384   (131072)
// L4: 512x256(KT=32, 32-shape) @ 147456  (131072)
// L5: 256x64 (KT=8,  16-shape) @ 278528  (16384)
// L6: 64x80  (KT=2,  16-shape) @ 294912  (5120, cols 75..79 zeroed)
// b6pad: 80 f32 @ short-offset 300032
#define P2_OFF 0
#define P3_OFF 16384
#define P4_OFF 147456
#define P5_OFF 278528
#define P6_OFF 294912
#define B6_OFF 300032
#define PREP_W_TOTAL 300032
#define PREP_TOTAL (PREP_W_TOTAL + 80)

__global__ void prep_weights(const float* __restrict__ w2, const float* __restrict__ w3,
                             const float* __restrict__ w4, const float* __restrict__ w5,
                             const float* __restrict__ w6, const float* __restrict__ b6,
                             short* __restrict__ ws) {
    int idx = blockIdx.x * blockDim.x + threadIdx.x;
    if (idx >= PREP_TOTAL) return;
    if (idx >= PREP_W_TOTAL) {                   // padded bias6 as float
        int n = idx - PREP_W_TOTAL;
        ((float*)(ws + B6_OFF))[n] = (n < 75) ? b6[n] : 0.0f;
        return;
    }
    int rel, KT, N;
    bool s32;
    const float* W;
    if (idx < P3_OFF)      { rel = idx - P2_OFF; KT = 2;  N = 256; W = w2; s32 = false; }
    else if (idx < P4_OFF) { rel = idx - P3_OFF; KT = 16; N = 512; W = w3; s32 = true;  }
    else if (idx < P5_OFF) { rel = idx - P4_OFF; KT = 32; N = 256; W = w4; s32 = true;  }
    else if (idx < P6_OFF) { rel = idx - P5_OFF; KT = 8;  N = 64;  W = w5; s32 = false; }
    else                   { rel = idx - P6_OFF; KT = 2;  N = 80;  W = w6; s32 = false; }
    int f = rel >> 9, r = rel & 511, lane = r >> 3, e = r & 7;
    int kt = f % KT, ot = f / KT;
    int n, k;
    if (s32) { n = ot * 32 + (lane & 31); k = kt * 16 + (lane >> 5) * 8 + e; }
    else     { n = ot * 16 + (lane & 15); k = kt * 32 + (lane >> 4) * 8 + e; }
    float v;
    if (N == 80) v = (n < 75) ? w6[k * 75 + n] : 0.0f;   // true row stride 75
    else         v = W[k * N + n];
    ws[idx] = f2bf(v);
}

// ---- 16x16x32 role-swapped layer (L2, L5, L6) -----------------------------
// D[od][pt] = sum_k W^T[od][k] * act[k][pt] (+bias[od])
// PTS: pt-tiles in block (M/16). PTG = PTS/NT point groups; OG = ODT/MT.
// DEP: rolling prefetch depth (compile-time; bufs statically indexed).
template<int K, int ODT, int PTS, int MT, int NT, int KTS, int DEP,
         bool RELU, bool OUTF32, bool INIT, bool STORE>
__device__ __forceinline__ void mlp_layer(f32x4 (&acc)[MT][NT],
                                          const short* __restrict__ act, const int sIn,
                                          void* __restrict__ outP, const int sOut,
                                          const short* __restrict__ pack,
                                          const float* __restrict__ bias,
                                          const int kt0,
                                          const int wave, const int lane) {
    constexpr int PTG = PTS / NT;        // point groups
    constexpr int OG  = ODT / MT;        // od groups
    constexpr int KT  = K / 32;          // k-tiles this pass
    constexpr int D   = (DEP < KT) ? DEP : KT;
    const int og = wave / PTG;
    if (og >= OG) return;
    const int ptb = (wave % PTG) * (NT * 16);
    const int otb = og * MT;
    const int lr = lane & 15, lq = lane >> 4;

    if (INIT) {
        #pragma unroll
        for (int i = 0; i < MT; ++i) {
            f32x4 bv = *(const f32x4*)(bias + (otb + i) * 16 + lq * 4);
            #pragma unroll
            for (int j = 0; j < NT; ++j) acc[i][j] = bv;
        }
    }

    const short* ap = pack + ((otb * KTS + kt0) << 9) + (lane << 3);
    const short* bp = act + (ptb + lr) * sIn + lq * 8;

    bf16x8 a[D][MT], b[D][NT];
    #pragma unroll
    for (int t = 0; t < D; ++t) {
        #pragma unroll
        for (int i = 0; i < MT; ++i) a[t][i] = *(const bf16x8*)(ap + ((i * KTS + t) << 9));
        #pragma unroll
        for (int j = 0; j < NT; ++j) b[t][j] = *(const bf16x8*)(bp + j * 16 * sIn + t * 32);
    }
    #pragma unroll
    for (int kt = 0; kt < KT; ++kt) {
        #pragma unroll
        for (int i = 0; i < MT; ++i) {
            #pragma unroll
            for (int j = 0; j < NT; ++j)
                acc[i][j] = __builtin_amdgcn_mfma_f32_16x16x32_bf16(a[kt % D][i], b[kt % D][j], acc[i][j], 0, 0, 0);
        }
        if (kt + D < KT) {
            #pragma unroll
            for (int i = 0; i < MT; ++i) a[kt % D][i] = *(const bf16x8*)(ap + ((i * KTS + kt + D) << 9));
            #pragma unroll
            for (int j = 0; j < NT; ++j) b[kt % D][j] = *(const bf16x8*)(bp + j * 16 * sIn + (kt + D) * 32);
        }
    }

    if (STORE) {
        #pragma unroll
        for (int i = 0; i < MT; ++i) {
            #pragma unroll
            for (int j = 0; j < NT; ++j) {
                const int row = ptb + j * 16 + lr;          // point
                const int col = (otb + i) * 16 + lq * 4;    // output dim (4 contiguous)
                if (OUTF32) {
                    *(f32x4*)((float*)outP + row * sOut + col) = acc[i][j];
                } else {
                    f32x4 v = acc[i][j];
                    if (RELU) {
                        v[0] = fmaxf(v[0], 0.0f); v[1] = fmaxf(v[1], 0.0f);
                        v[2] = fmaxf(v[2], 0.0f); v[3] = fmaxf(v[3], 0.0f);
                    }
                    bf16x4 pk = (bf16x4){ f2bf(v[0]), f2bf(v[1]), f2bf(v[2]), f2bf(v[3]) };
                    *(bf16x4*)((short*)outP + row * sOut + col) = pk;
                }
            }
        }
    }
}

// ---- 32x32x16 role-swapped layer (L3, L4) ---------------------------------
//  A: lane -> A[od = otb*32 + (lane&31)][k = kt*16 + (lane>>5)*8 + e]
//  B: lane -> act[pt = ptb + (lane&31)][k = kt*16 + (lane>>5)*8 + e]
//  D (m74/m101 layout): pt = lane&31, od = (r&3) + 8*(r>>2) + 4*(lane>>5)
// PTS: pt-tiles (M/32). PTG = PTS/NT; OG = OT/MT.
template<int K, int OT, int PTS, int MT, int NT, int KTS, int DEP,
         bool RELU, bool INIT, bool STORE>
__device__ __forceinline__ void mlp_layer32(f32x16 (&acc)[MT][NT],
                                            const short* __restrict__ act, const int sIn,
                                            short* __restrict__ outP, const int sOut,
                                            const short* __restrict__ pack,
                                            const float* __restrict__ bias,
                                            const int kt0,
                                            const int wave, const int lane) {
    constexpr int PTG = PTS / NT;
    constexpr int OG  = OT / MT;
    constexpr int KT  = K / 16;
    constexpr int D   = (DEP < KT) ? DEP : KT;
    const int og = wave / PTG;
    if (og >= OG) return;
    const int ptb = (wave % PTG) * (NT * 32);
    const int otb = og * MT;
    const int lr = lane & 31, hi = lane >> 5;

    if (INIT) {
        #pragma unroll
        for (int i = 0; i < MT; ++i) {
            #pragma unroll
            for (int rg = 0; rg < 4; ++rg) {
                f32x4 bv = *(const f32x4*)(bias + (otb + i) * 32 + rg * 8 + hi * 4);
                #pragma unroll
                for (int j = 0; j < NT; ++j) {
                    acc[i][j][rg * 4 + 0] = bv[0];
                    acc[i][j][rg * 4 + 1] = bv[1];
                    acc[i][j][rg * 4 + 2] = bv[2];
                    acc[i][j][rg * 4 + 3] = bv[3];
                }
            }
        }
    }

    const short* ap = pack + ((otb * KTS + kt0) << 9) + (lane << 3);
    const short* bp = act + (ptb + lr) * sIn + hi * 8;

    bf16x8 a[D][MT], b[D][NT];
    #pragma unroll
    for (int t = 0; t < D; ++t) {
        #pragma unroll
        for (int i = 0; i < MT; ++i) a[t][i] = *(const bf16x8*)(ap + ((i * KTS + t) << 9));
        #pragma unroll
        for (int j = 0; j < NT; ++j) b[t][j] = *(const bf16x8*)(bp + j * 32 * sIn + t * 16);
    }
    #pragma unroll
    for (int kt = 0; kt < KT; ++kt) {
        #pragma unroll
        for (int i = 0; i < MT; ++i) {
            #pragma unroll
            for (int j = 0; j < NT; ++j)
                acc[i][j] = __builtin_amdgcn_mfma_f32_32x32x16_bf16(a[kt % D][i], b[kt % D][j], acc[i][j], 0, 0, 0);
        }
        if (kt + D < KT) {
            #pragma unroll
            for (int i = 0; i < MT; ++i) a[kt % D][i] = *(const bf16x8*)(ap + ((i * KTS + kt + D) << 9));
            #pragma unroll
            for (int j = 0; j < NT; ++j) b[kt % D][j] = *(const bf16x8*)(bp + j * 32 * sIn + (kt + D) * 16);
        }
    }

    if (STORE) {
        #pragma unroll
        for (int i = 0; i < MT; ++i) {
            #pragma unroll
            for (int j = 0; j < NT; ++j) {
                const int row = ptb + j * 32 + lr;
                #pragma unroll
                for (int rg = 0; rg < 4; ++rg) {
                    float v0 = acc[i][j][rg * 4 + 0], v1 = acc[i][j][rg * 4 + 1],
                          v2 = acc[i][j][rg * 4 + 2], v3 = acc[i][j][rg * 4 + 3];
                    if (RELU) {
                        v0 = fmaxf(v0, 0.0f); v1 = fmaxf(v1, 0.0f);
                        v2 = fmaxf(v2, 0.0f); v3 = fmaxf(v3, 0.0f);
                    }
                    bf16x4 pk = (bf16x4){ f2bf(v0), f2bf(v1), f2bf(v2), f2bf(v3) };
                    *(bf16x4*)(outP + row * sOut + (otb + i) * 32 + rg * 8 + hi * 4) = pk;
                }
            }
        }
    }
}

__global__ __launch_bounds__(512, 2) void gridnet_fused(
    const float* __restrict__ pos, const float* __restrict__ grid_pos,
    const float* __restrict__ w1, const float* __restrict__ b1,
    const float* __restrict__ b2, const float* __restrict__ b3,
    const float* __restrict__ b4, const float* __restrict__ b5,
    const short* __restrict__ ws, float* __restrict__ out) {

    // M=128 points/block. region1: h2 -> h4 -> logits(f32).
    // region2: h3a -> h3b.  region3: h1 -> h5.
    // LDS = 67584 + 67584 + 18432 + 1024 = 154624 B -> 1 block/CU (8 waves).
    __shared__ short region1[128 * 264];
    __shared__ short region2[128 * 264];
    __shared__ short region3[128 * 72];
    __shared__ float posS[256];
    float* logitsS = (float*)region1;    // 128*80*4 = 40960 <= 67584

    const int tid  = threadIdx.x;
    const int wave = tid >> 6;
    const int lane = tid & 63;
    const int m0   = blockIdx.x * 128;

    if (tid < 256) posS[tid] = pos[m0 * 2 + tid];
    __syncthreads();

    // ---- layer 1 (2 -> 64), VALU; h1 stored [pt][dim] stride 72 ----
    #pragma unroll
    for (int r = 0; r < 16; ++r) {
        int idx = tid + r * 512;          // 128 pts x 64 dims
        int m = idx >> 6, n = idx & 63;
        float v = fmaf(posS[m * 2 + 0], w1[n], fmaf(posS[m * 2 + 1], w1[64 + n], b1[n]));
        region3[m * 72 + n] = f2bf(fmaxf(v, 0.0f));
    }
    __syncthreads();

    {   // L2: 64 -> 256 (16-shape). PTS=8: PTG=2 x OG=4, MT=4, NT=4.
        f32x4 acc[4][4];
        mlp_layer< 64, 16, 8, 4, 4,  2, 2, true, false, true, true>(
            acc, region3, 72, region1, 264, ws + P2_OFF, b2, 0, wave, lane);
    }
    __syncthreads();

    {   // L3/L4 halves; acc4 (64 VGPR) lives across. 32-shape PTS=4: PTG=2 x OG=4.
        f32x16 acc4[2][2];
        {   // L3a: h2 -> h3a (od 0..255)
            f32x16 acc[2][2];
            mlp_layer32<256, 8, 4, 2, 2, 16, 4, true, true, true>(
                acc, region1, 264, region2, 264, ws + P3_OFF, b3, 0, wave, lane);
        }
        __syncthreads();
        // L4 part 1: k = 0..255 (h3a), bias-init, no store
        mlp_layer32<256, 8, 4, 2, 2, 32, 4, true, true, false>(
            acc4, region2, 264, region1, 264, ws + P4_OFF, b4, 0, wave, lane);
        __syncthreads();
        {   // L3b: h2 -> h3b (od 256..511); depth 2 to cap VGPR with acc4 live
            f32x16 acc[2][2];
            mlp_layer32<256, 8, 4, 2, 2, 16, 2, true, true, true>(
                acc, region1, 264, region2, 264, ws + P3_OFF + 65536, b3 + 256,
                0, wave, lane);
        }
        __syncthreads();
        // L4 part 2: k = 256..511 (h3b; weight k-tiles 16..31), store h4
        mlp_layer32<256, 8, 4, 2, 2, 32, 4, true, false, true>(
            acc4, region2, 264, region1, 264, ws + P4_OFF, b4, 16, wave, lane);
    }
    __syncthreads();

    {   // L5: 256 -> 64 (16-shape). PTS=8: PTG=2 x OG=4, MT=1, NT=4.
        f32x4 acc[1][4];
        mlp_layer<256,  4, 8, 1, 4,  8, 4, true, false, true, true>(
            acc, region1, 264, region3, 72, ws + P5_OFF, b5, 0, wave, lane);
    }
    __syncthreads();

    {   // L6: 64 -> 80 logits (f32). PTS=8: PTG=1, NT=8; OG=8 guarded to 5.
        f32x4 acc[1][8];
        mlp_layer< 64,  5, 8, 1, 8,  2, 2, false, true, true, true>(
            acc, region3, 72, logitsS, 80, ws + P6_OFF,
            (const float*)(ws + B6_OFF), 0, wave, lane);
    }
    __syncthreads();

    // ---- epilogue: softmax(75) + 5x5x3 gather + sigmoid, 8 lanes/pt, 2 halves ----
    const int s = tid & 7;               // sub-lane
    #pragma unroll
    for (int half = 0; half < 2; ++half) {
        const int p = (tid >> 3) + half * 64;    // point within tile
        const float p0 = posS[p * 2 + 0], p1 = posS[p * 2 + 1];
        const int tx0 = (int)(p0 / PI_F * 1023.0f);
        const int ty0 = (int)((p1 + PI_F) / TWO_PI_F * 2047.0f);

        const float* lrow = logitsS + p * 80;
        float lv[10];
        float mx = -1e30f;
        #pragma unroll
        for (int i = 0; i < 10; ++i) {
            int f = s + i * 8;
            float v = (f < 75) ? lrow[f] : -1e30f;
            lv[i] = v;
            mx = fmaxf(mx, v);
        }
        mx = fmaxf(mx, __shfl_xor(mx, 1, 8));
        mx = fmaxf(mx, __shfl_xor(mx, 2, 8));
        mx = fmaxf(mx, __shfl_xor(mx, 4, 8));

        float den = 0.0f, x0 = 0.0f, x1 = 0.0f, x2 = 0.0f;
        #pragma unroll
        for (int i = 0; i < 10; ++i) {
            int f = s + i * 8;
            if (f < 75) {
                float e = __expf(lv[i] - mx);
                den += e;
                int c = f / 25, rr = f % 25, dy = rr / 5, dx = rr % 5;
                float g = grid_pos[((tx0 + dy) * 2052 + (ty0 + dx)) * 3 + c];
                if      (c == 0) x0 += e * g;
                else if (c == 1) x1 += e * g;
                else             x2 += e * g;
            }
        }
        #pragma unroll
        for (int mask = 1; mask < 8; mask <<= 1) {
            den += __shfl_xor(den, mask, 8);
            x0  += __shfl_xor(x0,  mask, 8);
            x1  += __shfl_xor(x1,  mask, 8);
            x2  += __shfl_xor(x2,  mask, 8);
        }
        if (s < 3) {
            float xv = (s == 0) ? x0 : (s == 1 ? x1 : x2);
            xv /= den;
            float sig = 1.0f / (1.0f + __expf(-xv));
            out[(m0 + p) * 3 + s] = (sig > 0.1f) ? sig * 255.0f : 0.0f;
        }
    }
}

extern "C" void kernel_launch(void* const* d_in, const int* in_sizes, int n_in,
                              void* d_out, int out_size, void* d_ws, size_t ws_size,
                              hipStream_t stream) {
    const float* pos      = (const float*)d_in[0];
    const float* grid_pos = (const float*)d_in[1];
    const float* w1 = (const float*)d_in[2];
    const float* b1 = (const float*)d_in[3];
    const float* w2 = (const float*)d_in[4];
    const float* b2 = (const float*)d_in[5];
    const float* w3 = (const float*)d_in[6];
    const float* b3 = (const float*)d_in[7];
    const float* w4 = (const float*)d_in[8];
    const float* b4 = (const float*)d_in[9];
    const float* w5 = (const float*)d_in[10];
    const float* b5 = (const float*)d_in[11];
    const float* w6 = (const float*)d_in[12];
    const float* b6 = (const float*)d_in[13];
    short* ws = (short*)d_ws;
    float* out = (float*)d_out;

    prep_weights<<<(PREP_TOTAL + 255) / 256, 256, 0, stream>>>(w2, w3, w4, w5, w6, b6, ws);
    gridnet_fused<<<262144 / 128, 512, 0, stream>>>(pos, grid_pos, w1, b1, b2, b3, b4, b5, ws, out);
}

// Round 6
// 295.491 us; speedup vs baseline: 1.0964x; 1.0964x over previous
//
#include <hip/hip_runtime.h>

// ---------------------------------------------------------------------------
// GridNet fused forward: MLP (bf16 MFMA) + softmax + 5x5 gather + sigmoid
// B=262144, GS=(1024,2048), NS=5, layers 2-64-256-512-256-64-75
// R5: 32x32x16 L3/L4, M=64, 2 blk/CU. 253us, MfmaUtil 27.8, VALU 33.
// R7: 3 blk/CU -> 262us. R8: M=128, MT2NT2, depth-4 PF, 1 blk/CU -> 253us.
//   => occupancy / per-iter ILP / prefetch depth are NOT the levers.
//   Accounting: MFMA 20k + VALU 20k + LDS 17k cyc/block ~= 57k ~= wall 76k:
//   pipes run SERIALIZED (phase-locked layers). VALU is ~16k cyc of manual
//   f2bf bit-twiddle (3-4 ops/elem on 147k elems/block) on the critical path.
// R9: (a) native bf16 converts (v_cvt_pk_bf16_f32 via __bf16 / convertvector,
//     ~6x fewer ops); (b) s_setprio(1) around MFMA clusters so MFMA-phase
//     waves preempt convert-phase waves of the other resident block;
//     (c) back to R5 geometry (M=64, 77.3KB LDS, 2 blk/CU) for cross-block
//     phase overlap.
// R10: identical resubmission (round 5 never acquired a GPU; no data).
// ---------------------------------------------------------------------------

#define PI_F     3.14159265358979323846f
#define TWO_PI_F 6.28318530717958647692f

typedef __attribute__((ext_vector_type(8))) short bf16x8;   // 8 bf16 = 4 VGPRs
typedef __attribute__((ext_vector_type(4))) short bf16x4;   // 8 B packed
typedef __attribute__((ext_vector_type(4))) float f32x4;    // 16x16 MFMA C/D
typedef __attribute__((ext_vector_type(16))) float f32x16;  // 32x32 MFMA C/D
typedef __attribute__((ext_vector_type(4))) __bf16 bfv4;

__device__ __forceinline__ short f2bf(float f) {            // RNE, 1 instr
    __bf16 b = (__bf16)f;
    return __builtin_bit_cast(short, b);
}
__device__ __forceinline__ bf16x4 cvt4(f32x4 v) {           // 2x v_cvt_pk_bf16_f32
    bfv4 b = __builtin_convertvector(v, bfv4);
    return __builtin_bit_cast(bf16x4, b);
}

// ws layout (shorts). Weights fragment-packed for MFMA A-operand.
// 16-shape layers (L2,L5,L6): frag f = ot*KT + kt (ot 16-wide, kt 32-deep):
//   lane*8+e <-> W[k = kt*32 + (lane>>4)*8 + e][n = ot*16 + (lane&15)]
// 32-shape layers (L3,L4):    frag f = ot*KT + kt (ot 32-wide, kt 16-deep):
//   lane*8+e <-> W[k = kt*16 + (lane>>5)*8 + e][n = ot*32 + (lane&31)]
// L2: 64x256 (KT=2,  16-shape) @ 0       (16384)
// L3: 256x512(KT=16, 32-shape) @ 16384   (131072)
// L4: 512x256(KT=32, 32-shape) @ 147456  (131072)
// L5: 256x64 (KT=8,  16-shape) @ 278528  (16384)
// L6: 64x80  (KT=2,  16-shape) @ 294912  (5120, cols 75..79 zeroed)
// b6pad: 80 f32 @ short-offset 300032
#define P2_OFF 0
#define P3_OFF 16384
#define P4_OFF 147456
#define P5_OFF 278528
#define P6_OFF 294912
#define B6_OFF 300032
#define PREP_W_TOTAL 300032
#define PREP_TOTAL (PREP_W_TOTAL + 80)

__global__ void prep_weights(const float* __restrict__ w2, const float* __restrict__ w3,
                             const float* __restrict__ w4, const float* __restrict__ w5,
                             const float* __restrict__ w6, const float* __restrict__ b6,
                             short* __restrict__ ws) {
    int idx = blockIdx.x * blockDim.x + threadIdx.x;
    if (idx >= PREP_TOTAL) return;
    if (idx >= PREP_W_TOTAL) {                   // padded bias6 as float
        int n = idx - PREP_W_TOTAL;
        ((float*)(ws + B6_OFF))[n] = (n < 75) ? b6[n] : 0.0f;
        return;
    }
    int rel, KT, N;
    bool s32;
    const float* W;
    if (idx < P3_OFF)      { rel = idx - P2_OFF; KT = 2;  N = 256; W = w2; s32 = false; }
    else if (idx < P4_OFF) { rel = idx - P3_OFF; KT = 16; N = 512; W = w3; s32 = true;  }
    else if (idx < P5_OFF) { rel = idx - P4_OFF; KT = 32; N = 256; W = w4; s32 = true;  }
    else if (idx < P6_OFF) { rel = idx - P5_OFF; KT = 8;  N = 64;  W = w5; s32 = false; }
    else                   { rel = idx - P6_OFF; KT = 2;  N = 80;  W = w6; s32 = false; }
    int f = rel >> 9, r = rel & 511, lane = r >> 3, e = r & 7;
    int kt = f % KT, ot = f / KT;
    int n, k;
    if (s32) { n = ot * 32 + (lane & 31); k = kt * 16 + (lane >> 5) * 8 + e; }
    else     { n = ot * 16 + (lane & 15); k = kt * 32 + (lane >> 4) * 8 + e; }
    float v;
    if (N == 80) v = (n < 75) ? w6[k * 75 + n] : 0.0f;   // true row stride 75
    else         v = W[k * N + n];
    ws[idx] = f2bf(v);
}

// ---- 16x16x32 role-swapped layer (L2, L5, L6) -----------------------------
// D[od][pt] = sum_k W^T[od][k] * act[k][pt] (+bias[od])
//  A (weights, fragment-packed): lane -> A[od=lane&15][k=(lane>>4)*8+j]
//  B (acts in LDS, [pt][dim], stride sIn): lane -> B[k=(lane>>4)*8+j][pt=lane&15]
//  D: pt = lane&15, od = (lane>>4)*4 + r  -> 4 contiguous dims, b64 write.
template<int K, int ODT, int MT, int NT, int KTS, int KT0,
         bool RELU, bool OUTF32, bool INIT, bool STORE, bool PF>
__device__ __forceinline__ void mlp_layer(f32x4 (&acc)[MT][NT],
                                          const short* __restrict__ act, const int sIn,
                                          void* __restrict__ outP, const int sOut,
                                          const short* __restrict__ pack,
                                          const float* __restrict__ bias,
                                          const int wave, const int lane) {
    constexpr int PTG = 4 / NT;          // point groups
    constexpr int OG  = ODT / MT;        // od groups
    constexpr int KT  = K / 32;          // k-tiles this pass
    const int og = wave / PTG;
    if (og >= OG) return;
    const int ptb = (wave % PTG) * (NT * 16);
    const int otb = og * MT;
    const int lr = lane & 15, lq = lane >> 4;

    if (INIT) {
        #pragma unroll
        for (int i = 0; i < MT; ++i) {
            f32x4 bv = *(const f32x4*)(bias + (otb + i) * 16 + lq * 4);
            #pragma unroll
            for (int j = 0; j < NT; ++j) acc[i][j] = bv;
        }
    }

    const short* ap = pack + ((otb * KTS + KT0) << 9) + (lane << 3);
    const short* bp = act + (ptb + lr) * sIn + lq * 8;

    if (PF) {
        bf16x8 a[MT], b[NT];
        #pragma unroll
        for (int i = 0; i < MT; ++i) a[i] = *(const bf16x8*)(ap + ((i * KTS) << 9));
        #pragma unroll
        for (int j = 0; j < NT; ++j) b[j] = *(const bf16x8*)(bp + j * 16 * sIn);

        #pragma unroll
        for (int kt = 0; kt < KT - 1; ++kt) {
            bf16x8 a2[MT], b2[NT];
            #pragma unroll
            for (int i = 0; i < MT; ++i) a2[i] = *(const bf16x8*)(ap + ((i * KTS + kt + 1) << 9));
            #pragma unroll
            for (int j = 0; j < NT; ++j) b2[j] = *(const bf16x8*)(bp + j * 16 * sIn + (kt + 1) * 32);
            __builtin_amdgcn_s_setprio(1);
            #pragma unroll
            for (int i = 0; i < MT; ++i) {
                #pragma unroll
                for (int j = 0; j < NT; ++j)
                    acc[i][j] = __builtin_amdgcn_mfma_f32_16x16x32_bf16(a[i], b[j], acc[i][j], 0, 0, 0);
            }
            __builtin_amdgcn_s_setprio(0);
            #pragma unroll
            for (int i = 0; i < MT; ++i) a[i] = a2[i];
            #pragma unroll
            for (int j = 0; j < NT; ++j) b[j] = b2[j];
        }
        __builtin_amdgcn_s_setprio(1);
        #pragma unroll
        for (int i = 0; i < MT; ++i) {
            #pragma unroll
            for (int j = 0; j < NT; ++j)
                acc[i][j] = __builtin_amdgcn_mfma_f32_16x16x32_bf16(a[i], b[j], acc[i][j], 0, 0, 0);
        }
        __builtin_amdgcn_s_setprio(0);
    } else {
        #pragma unroll
        for (int kt = 0; kt < KT; ++kt) {
            bf16x8 a[MT], b[NT];
            #pragma unroll
            for (int i = 0; i < MT; ++i) a[i] = *(const bf16x8*)(ap + ((i * KTS + kt) << 9));
            #pragma unroll
            for (int j = 0; j < NT; ++j) b[j] = *(const bf16x8*)(bp + j * 16 * sIn + kt * 32);
            __builtin_amdgcn_s_setprio(1);
            #pragma unroll
            for (int i = 0; i < MT; ++i) {
                #pragma unroll
                for (int j = 0; j < NT; ++j)
                    acc[i][j] = __builtin_amdgcn_mfma_f32_16x16x32_bf16(a[i], b[j], acc[i][j], 0, 0, 0);
            }
            __builtin_amdgcn_s_setprio(0);
        }
    }

    if (STORE) {
        #pragma unroll
        for (int i = 0; i < MT; ++i) {
            #pragma unroll
            for (int j = 0; j < NT; ++j) {
                const int row = ptb + j * 16 + lr;          // point
                const int col = (otb + i) * 16 + lq * 4;    // output dim (4 contiguous)
                if (OUTF32) {
                    *(f32x4*)((float*)outP + row * sOut + col) = acc[i][j];
                } else {
                    f32x4 v = acc[i][j];
                    if (RELU) {
                        v[0] = fmaxf(v[0], 0.0f); v[1] = fmaxf(v[1], 0.0f);
                        v[2] = fmaxf(v[2], 0.0f); v[3] = fmaxf(v[3], 0.0f);
                    }
                    *(bf16x4*)((short*)outP + row * sOut + col) = cvt4(v);
                }
            }
        }
    }
}

// ---- 32x32x16 role-swapped layer (L3, L4) ---------------------------------
//  A: lane -> A[od = otb*32 + (lane&31)][k = kt*16 + (lane>>5)*8 + e]
//  B: lane -> act[pt = ptb + (lane&31)][k = kt*16 + (lane>>5)*8 + e]
//  D (m74/m101 layout): pt = lane&31, od = (r&3) + 8*(r>>2) + 4*(lane>>5)
//    -> per rg=r>>2: 4 contiguous ods at 8*rg + 4*hi => b64 packed write.
template<int K, int OT, int MT, int NT, int KTS, int KT0,
         bool RELU, bool INIT, bool STORE, bool PF>
__device__ __forceinline__ void mlp_layer32(f32x16 (&acc)[MT][NT],
                                            const short* __restrict__ act, const int sIn,
                                            short* __restrict__ outP, const int sOut,
                                            const short* __restrict__ pack,
                                            const float* __restrict__ bias,
                                            const int wave, const int lane) {
    constexpr int PTG = 2 / NT;
    constexpr int OG  = OT / MT;
    constexpr int KT  = K / 16;
    const int og = wave / PTG;
    if (og >= OG) return;
    const int ptb = (wave % PTG) * (NT * 32);
    const int otb = og * MT;
    const int lr = lane & 31, hi = lane >> 5;

    if (INIT) {
        #pragma unroll
        for (int i = 0; i < MT; ++i) {
            #pragma unroll
            for (int rg = 0; rg < 4; ++rg) {
                f32x4 bv = *(const f32x4*)(bias + (otb + i) * 32 + rg * 8 + hi * 4);
                #pragma unroll
                for (int j = 0; j < NT; ++j) {
                    acc[i][j][rg * 4 + 0] = bv[0];
                    acc[i][j][rg * 4 + 1] = bv[1];
                    acc[i][j][rg * 4 + 2] = bv[2];
                    acc[i][j][rg * 4 + 3] = bv[3];
                }
            }
        }
    }

    const short* ap = pack + ((otb * KTS + KT0) << 9) + (lane << 3);
    const short* bp = act + (ptb + lr) * sIn + hi * 8;

    if (PF) {
        bf16x8 a[MT], b[NT];
        #pragma unroll
        for (int i = 0; i < MT; ++i) a[i] = *(const bf16x8*)(ap + ((i * KTS) << 9));
        #pragma unroll
        for (int j = 0; j < NT; ++j) b[j] = *(const bf16x8*)(bp + j * 32 * sIn);

        #pragma unroll
        for (int kt = 0; kt < KT - 1; ++kt) {
            bf16x8 a2[MT], b2[NT];
            #pragma unroll
            for (int i = 0; i < MT; ++i) a2[i] = *(const bf16x8*)(ap + ((i * KTS + kt + 1) << 9));
            #pragma unroll
            for (int j = 0; j < NT; ++j) b2[j] = *(const bf16x8*)(bp + j * 32 * sIn + (kt + 1) * 16);
            __builtin_amdgcn_s_setprio(1);
            #pragma unroll
            for (int i = 0; i < MT; ++i) {
                #pragma unroll
                for (int j = 0; j < NT; ++j)
                    acc[i][j] = __builtin_amdgcn_mfma_f32_32x32x16_bf16(a[i], b[j], acc[i][j], 0, 0, 0);
            }
            __builtin_amdgcn_s_setprio(0);
            #pragma unroll
            for (int i = 0; i < MT; ++i) a[i] = a2[i];
            #pragma unroll
            for (int j = 0; j < NT; ++j) b[j] = b2[j];
        }
        __builtin_amdgcn_s_setprio(1);
        #pragma unroll
        for (int i = 0; i < MT; ++i) {
            #pragma unroll
            for (int j = 0; j < NT; ++j)
                acc[i][j] = __builtin_amdgcn_mfma_f32_32x32x16_bf16(a[i], b[j], acc[i][j], 0, 0, 0);
        }
        __builtin_amdgcn_s_setprio(0);
    } else {
        #pragma unroll
        for (int kt = 0; kt < KT; ++kt) {
            bf16x8 a[MT], b[NT];
            #pragma unroll
            for (int i = 0; i < MT; ++i) a[i] = *(const bf16x8*)(ap + ((i * KTS + kt) << 9));
            #pragma unroll
            for (int j = 0; j < NT; ++j) b[j] = *(const bf16x8*)(bp + j * 32 * sIn + kt * 16);
            __builtin_amdgcn_s_setprio(1);
            #pragma unroll
            for (int i = 0; i < MT; ++i) {
                #pragma unroll
                for (int j = 0; j < NT; ++j)
                    acc[i][j] = __builtin_amdgcn_mfma_f32_32x32x16_bf16(a[i], b[j], acc[i][j], 0, 0, 0);
            }
            __builtin_amdgcn_s_setprio(0);
        }
    }

    if (STORE) {
        #pragma unroll
        for (int i = 0; i < MT; ++i) {
            #pragma unroll
            for (int j = 0; j < NT; ++j) {
                const int row = ptb + j * 32 + lr;
                #pragma unroll
                for (int rg = 0; rg < 4; ++rg) {
                    f32x4 v;
                    v[0] = acc[i][j][rg * 4 + 0]; v[1] = acc[i][j][rg * 4 + 1];
                    v[2] = acc[i][j][rg * 4 + 2]; v[3] = acc[i][j][rg * 4 + 3];
                    if (RELU) {
                        v[0] = fmaxf(v[0], 0.0f); v[1] = fmaxf(v[1], 0.0f);
                        v[2] = fmaxf(v[2], 0.0f); v[3] = fmaxf(v[3], 0.0f);
                    }
                    *(bf16x4*)(outP + row * sOut + (otb + i) * 32 + rg * 8 + hi * 4) = cvt4(v);
                }
            }
        }
    }
}

__global__ __launch_bounds__(512, 4) void gridnet_fused(
    const float* __restrict__ pos, const float* __restrict__ grid_pos,
    const float* __restrict__ w1, const float* __restrict__ b1,
    const float* __restrict__ b2, const float* __restrict__ b3,
    const float* __restrict__ b4, const float* __restrict__ b5,
    const short* __restrict__ ws, float* __restrict__ out) {

    // region1: h2, then h4.   region2: h3a/h3b, then logits (f32).
    // region3: h1, then h5.   Peak LDS = 33792+33792+9216+512 = 77312 B -> 2 blk/CU.
    __shared__ short region1[64 * 264];
    __shared__ short region2[64 * 264];
    __shared__ short region3[64 * 72];
    __shared__ float posS[128];
    float* logitsS = (float*)region2;    // 64*80*4 = 20480 <= 33792

    const int tid  = threadIdx.x;
    const int wave = tid >> 6;
    const int lane = tid & 63;
    const int m0   = blockIdx.x * 64;

    if (tid < 128) posS[tid] = pos[m0 * 2 + tid];
    __syncthreads();

    // ---- layer 1 (2 -> 64), VALU; h1 stored [pt][dim] stride 72 ----
    #pragma unroll
    for (int r = 0; r < 8; ++r) {
        int idx = tid + r * 512;          // 64 pts x 64 dims
        int m = idx >> 6, n = idx & 63;
        float v = fmaf(posS[m * 2 + 0], w1[n], fmaf(posS[m * 2 + 1], w1[64 + n], b1[n]));
        region3[m * 72 + n] = f2bf(fmaxf(v, 0.0f));
    }
    __syncthreads();

    {   // L2: 64 -> 256 (16-shape)
        f32x4 acc[2][4];
        mlp_layer< 64, 16, 2, 4,  2, 0, true, false, true, true, true>(
            acc, region3, 72, region1, 264, ws + P2_OFF, b2, wave, lane);
    }
    __syncthreads();

    {   // L4 accumulator lives across both halves (32-shape, 32 VGPRs)
        f32x16 acc4[2][1];
        {   // L3a: h2 -> h3a (od 0..255)
            f32x16 acc[2][1];
            mlp_layer32<256, 8, 2, 1, 16, 0, true, true, true, true>(
                acc, region1, 264, region2, 264, ws + P3_OFF, b3, wave, lane);
        }
        __syncthreads();
        // L4 part 1: k = 0..255 (h3a), bias-init, no store
        mlp_layer32<256, 8, 2, 1, 32, 0, true, true, false, true>(
            acc4, region2, 264, region1, 264, ws + P4_OFF, b4, wave, lane);
        __syncthreads();
        {   // L3b: h2 -> h3b (od 256..511)
            f32x16 acc[2][1];
            mlp_layer32<256, 8, 2, 1, 16, 0, true, true, true, true>(
                acc, region1, 264, region2, 264, ws + P3_OFF + (16 * 8 * 512), b3 + 256,
                wave, lane);
        }
        __syncthreads();
        // L4 part 2: k = 256..511 (h3b, local k 0..255; weight k-tiles 16..31), store h4
        mlp_layer32<256, 8, 2, 1, 32, 16, true, false, true, true>(
            acc4, region2, 264, region1, 264, ws + P4_OFF, b4, wave, lane);
    }
    __syncthreads();

    {   // L5: 256 -> 64 (16-shape)
        f32x4 acc[1][2];
        mlp_layer<256,  4, 1, 2,  8, 0, true, false, true, true, true>(
            acc, region1, 264, region3, 72, ws + P5_OFF, b5, wave, lane);
    }
    __syncthreads();

    {   // L6: 64 -> 80 logits (f32, 16-shape)
        f32x4 acc[1][4];
        mlp_layer< 64,  5, 1, 4,  2, 0, false, true, true, true, true>(
            acc, region3, 72, logitsS, 80, ws + P6_OFF,
            (const float*)(ws + B6_OFF), wave, lane);
    }
    __syncthreads();

    // ---- epilogue: softmax(75) + 5x5x3 gather + sigmoid, 8 lanes per point ----
    const int p = tid >> 3;              // point within tile
    const int s = tid & 7;               // sub-lane
    const float p0 = posS[p * 2 + 0], p1 = posS[p * 2 + 1];
    const int tx0 = (int)(p0 / PI_F * 1023.0f);                 // == int(gx), ix = tx0 + dy
    const int ty0 = (int)((p1 + PI_F) / TWO_PI_F * 2047.0f);    // == int(gy), iy = ty0 + dx

    const float* lrow = logitsS + p * 80;
    float lv[10];
    float mx = -1e30f;
    #pragma unroll
    for (int i = 0; i < 10; ++i) {
        int f = s + i * 8;
        float v = (f < 75) ? lrow[f] : -1e30f;
        lv[i] = v;
        mx = fmaxf(mx, v);
    }
    mx = fmaxf(mx, __shfl_xor(mx, 1, 8));
    mx = fmaxf(mx, __shfl_xor(mx, 2, 8));
    mx = fmaxf(mx, __shfl_xor(mx, 4, 8));

    float den = 0.0f, x0 = 0.0f, x1 = 0.0f, x2 = 0.0f;
    #pragma unroll
    for (int i = 0; i < 10; ++i) {
        int f = s + i * 8;
        if (f < 75) {
            float e = __expf(lv[i] - mx);
            den += e;
            int c = f / 25, rr = f % 25, dy = rr / 5, dx = rr % 5;
            float g = grid_pos[((tx0 + dy) * 2052 + (ty0 + dx)) * 3 + c];
            if      (c == 0) x0 += e * g;
            else if (c == 1) x1 += e * g;
            else             x2 += e * g;
        }
    }
    #pragma unroll
    for (int mask = 1; mask < 8; mask <<= 1) {
        den += __shfl_xor(den, mask, 8);
        x0  += __shfl_xor(x0,  mask, 8);
        x1  += __shfl_xor(x1,  mask, 8);
        x2  += __shfl_xor(x2,  mask, 8);
    }
    if (s < 3) {
        float xv = (s == 0) ? x0 : (s == 1 ? x1 : x2);
        xv /= den;
        float sig = 1.0f / (1.0f + __expf(-xv));
        out[(m0 + p) * 3 + s] = (sig > 0.1f) ? sig * 255.0f : 0.0f;
    }
}

extern "C" void kernel_launch(void* const* d_in, const int* in_sizes, int n_in,
                              void* d_out, int out_size, void* d_ws, size_t ws_size,
                              hipStream_t stream) {
    const float* pos      = (const float*)d_in[0];
    const float* grid_pos = (const float*)d_in[1];
    const float* w1 = (const float*)d_in[2];
    const float* b1 = (const float*)d_in[3];
    const float* w2 = (const float*)d_in[4];
    const float* b2 = (const float*)d_in[5];
    const float* w3 = (const float*)d_in[6];
    const float* b3 = (const float*)d_in[7];
    const float* w4 = (const float*)d_in[8];
    const float* b4 = (const float*)d_in[9];
    const float* w5 = (const float*)d_in[10];
    const float* b5 = (const float*)d_in[11];
    const float* w6 = (const float*)d_in[12];
    const float* b6 = (const float*)d_in[13];
    short* ws = (short*)d_ws;
    float* out = (float*)d_out;

    prep_weights<<<(PREP_TOTAL + 255) / 256, 256, 0, stream>>>(w2, w3, w4, w5, w6, b6, ws);
    gridnet_fused<<<262144 / 64, 512, 0, stream>>>(pos, grid_pos, w1, b1, b2, b3, b4, b5, ws, out);
}

// Round 7
// 293.979 us; speedup vs baseline: 1.1021x; 1.0051x over previous
//
#include <hip/hip_runtime.h>

// ---------------------------------------------------------------------------
// GridNet fused forward: MLP (bf16 MFMA) + softmax + 5x5 gather + sigmoid
// B=262144, GS=(1024,2048), NS=5, layers 2-64-256-512-256-64-75
// R5: 32x32x16 L3/L4, M=64, 2 blk/CU: 253us, MfmaUtil 27.8.
// R7: 3 blk/CU: 262. R8: M=128 + rolling depth-4 PF, 1 blk/CU: 253.
// R9: cvt_pk converts + setprio: 240us, VALU 33->27, MfmaUtil 28.4.
// Model fitting all rounds: MfmaUtil = duty x waves/SIMD, duty = MFMA-cyc /
//   (~200cyc exposed per-iter load latency). R8's rolling prefetch never
//   deepened the pipeline (per-iter interleave defeats counted waits).
// R11: L3/L4 k-loops -> chunked double-buffered BATCH loads (m97 pattern:
//   issue all chunk c+1 loads, then MFMA chunk c; compiler emits counted
//   vmcnt/lgkmcnt for this shape). CH=2 (4 MFMA / 6 loads per chunk);
//   L3b CH=1 (acc4 live, VGPR cap 128). Predict MfmaUtil 38-48, ~190us.
// ---------------------------------------------------------------------------

#define PI_F     3.14159265358979323846f
#define TWO_PI_F 6.28318530717958647692f

typedef __attribute__((ext_vector_type(8))) short bf16x8;   // 8 bf16 = 4 VGPRs
typedef __attribute__((ext_vector_type(4))) short bf16x4;   // 8 B packed
typedef __attribute__((ext_vector_type(4))) float f32x4;    // 16x16 MFMA C/D
typedef __attribute__((ext_vector_type(16))) float f32x16;  // 32x32 MFMA C/D
typedef __attribute__((ext_vector_type(4))) __bf16 bfv4;

__device__ __forceinline__ short f2bf(float f) {            // RNE, 1 instr
    __bf16 b = (__bf16)f;
    return __builtin_bit_cast(short, b);
}
__device__ __forceinline__ bf16x4 cvt4(f32x4 v) {           // 2x v_cvt_pk_bf16_f32
    bfv4 b = __builtin_convertvector(v, bfv4);
    return __builtin_bit_cast(bf16x4, b);
}

// ws layout (shorts). Weights fragment-packed for MFMA A-operand.
// 16-shape layers (L2,L5,L6): frag f = ot*KT + kt (ot 16-wide, kt 32-deep):
//   lane*8+e <-> W[k = kt*32 + (lane>>4)*8 + e][n = ot*16 + (lane&15)]
// 32-shape layers (L3,L4):    frag f = ot*KT + kt (ot 32-wide, kt 16-deep):
//   lane*8+e <-> W[k = kt*16 + (lane>>5)*8 + e][n = ot*32 + (lane&31)]
// L2: 64x256 (KT=2,  16-shape) @ 0       (16384)
// L3: 256x512(KT=16, 32-shape) @ 16384   (131072)
// L4: 512x256(KT=32, 32-shape) @ 147456  (131072)
// L5: 256x64 (KT=8,  16-shape) @ 278528  (16384)
// L6: 64x80  (KT=2,  16-shape) @ 294912  (5120, cols 75..79 zeroed)
// b6pad: 80 f32 @ short-offset 300032
#define P2_OFF 0
#define P3_OFF 16384
#define P4_OFF 147456
#define P5_OFF 278528
#define P6_OFF 294912
#define B6_OFF 300032
#define PREP_W_TOTAL 300032
#define PREP_TOTAL (PREP_W_TOTAL + 80)

__global__ void prep_weights(const float* __restrict__ w2, const float* __restrict__ w3,
                             const float* __restrict__ w4, const float* __restrict__ w5,
                             const float* __restrict__ w6, const float* __restrict__ b6,
                             short* __restrict__ ws) {
    int idx = blockIdx.x * blockDim.x + threadIdx.x;
    if (idx >= PREP_TOTAL) return;
    if (idx >= PREP_W_TOTAL) {                   // padded bias6 as float
        int n = idx - PREP_W_TOTAL;
        ((float*)(ws + B6_OFF))[n] = (n < 75) ? b6[n] : 0.0f;
        return;
    }
    int rel, KT, N;
    bool s32;
    const float* W;
    if (idx < P3_OFF)      { rel = idx - P2_OFF; KT = 2;  N = 256; W = w2; s32 = false; }
    else if (idx < P4_OFF) { rel = idx - P3_OFF; KT = 16; N = 512; W = w3; s32 = true;  }
    else if (idx < P5_OFF) { rel = idx - P4_OFF; KT = 32; N = 256; W = w4; s32 = true;  }
    else if (idx < P6_OFF) { rel = idx - P5_OFF; KT = 8;  N = 64;  W = w5; s32 = false; }
    else                   { rel = idx - P6_OFF; KT = 2;  N = 80;  W = w6; s32 = false; }
    int f = rel >> 9, r = rel & 511, lane = r >> 3, e = r & 7;
    int kt = f % KT, ot = f / KT;
    int n, k;
    if (s32) { n = ot * 32 + (lane & 31); k = kt * 16 + (lane >> 5) * 8 + e; }
    else     { n = ot * 16 + (lane & 15); k = kt * 32 + (lane >> 4) * 8 + e; }
    float v;
    if (N == 80) v = (n < 75) ? w6[k * 75 + n] : 0.0f;   // true row stride 75
    else         v = W[k * N + n];
    ws[idx] = f2bf(v);
}

// ---- 16x16x32 role-swapped layer (L2, L5, L6) -----------------------------
// D[od][pt] = sum_k W^T[od][k] * act[k][pt] (+bias[od])
//  A (weights, fragment-packed): lane -> A[od=lane&15][k=(lane>>4)*8+j]
//  B (acts in LDS, [pt][dim], stride sIn): lane -> B[k=(lane>>4)*8+j][pt=lane&15]
//  D: pt = lane&15, od = (lane>>4)*4 + r  -> 4 contiguous dims, b64 write.
template<int K, int ODT, int MT, int NT, int KTS, int KT0,
         bool RELU, bool OUTF32, bool INIT, bool STORE, bool PF>
__device__ __forceinline__ void mlp_layer(f32x4 (&acc)[MT][NT],
                                          const short* __restrict__ act, const int sIn,
                                          void* __restrict__ outP, const int sOut,
                                          const short* __restrict__ pack,
                                          const float* __restrict__ bias,
                                          const int wave, const int lane) {
    constexpr int PTG = 4 / NT;          // point groups
    constexpr int OG  = ODT / MT;        // od groups
    constexpr int KT  = K / 32;          // k-tiles this pass
    const int og = wave / PTG;
    if (og >= OG) return;
    const int ptb = (wave % PTG) * (NT * 16);
    const int otb = og * MT;
    const int lr = lane & 15, lq = lane >> 4;

    if (INIT) {
        #pragma unroll
        for (int i = 0; i < MT; ++i) {
            f32x4 bv = *(const f32x4*)(bias + (otb + i) * 16 + lq * 4);
            #pragma unroll
            for (int j = 0; j < NT; ++j) acc[i][j] = bv;
        }
    }

    const short* ap = pack + ((otb * KTS + KT0) << 9) + (lane << 3);
    const short* bp = act + (ptb + lr) * sIn + lq * 8;

    if (PF) {
        bf16x8 a[MT], b[NT];
        #pragma unroll
        for (int i = 0; i < MT; ++i) a[i] = *(const bf16x8*)(ap + ((i * KTS) << 9));
        #pragma unroll
        for (int j = 0; j < NT; ++j) b[j] = *(const bf16x8*)(bp + j * 16 * sIn);

        #pragma unroll
        for (int kt = 0; kt < KT - 1; ++kt) {
            bf16x8 a2[MT], b2[NT];
            #pragma unroll
            for (int i = 0; i < MT; ++i) a2[i] = *(const bf16x8*)(ap + ((i * KTS + kt + 1) << 9));
            #pragma unroll
            for (int j = 0; j < NT; ++j) b2[j] = *(const bf16x8*)(bp + j * 16 * sIn + (kt + 1) * 32);
            __builtin_amdgcn_s_setprio(1);
            #pragma unroll
            for (int i = 0; i < MT; ++i) {
                #pragma unroll
                for (int j = 0; j < NT; ++j)
                    acc[i][j] = __builtin_amdgcn_mfma_f32_16x16x32_bf16(a[i], b[j], acc[i][j], 0, 0, 0);
            }
            __builtin_amdgcn_s_setprio(0);
            #pragma unroll
            for (int i = 0; i < MT; ++i) a[i] = a2[i];
            #pragma unroll
            for (int j = 0; j < NT; ++j) b[j] = b2[j];
        }
        __builtin_amdgcn_s_setprio(1);
        #pragma unroll
        for (int i = 0; i < MT; ++i) {
            #pragma unroll
            for (int j = 0; j < NT; ++j)
                acc[i][j] = __builtin_amdgcn_mfma_f32_16x16x32_bf16(a[i], b[j], acc[i][j], 0, 0, 0);
        }
        __builtin_amdgcn_s_setprio(0);
    } else {
        #pragma unroll
        for (int kt = 0; kt < KT; ++kt) {
            bf16x8 a[MT], b[NT];
            #pragma unroll
            for (int i = 0; i < MT; ++i) a[i] = *(const bf16x8*)(ap + ((i * KTS + kt) << 9));
            #pragma unroll
            for (int j = 0; j < NT; ++j) b[j] = *(const bf16x8*)(bp + j * 16 * sIn + kt * 32);
            __builtin_amdgcn_s_setprio(1);
            #pragma unroll
            for (int i = 0; i < MT; ++i) {
                #pragma unroll
                for (int j = 0; j < NT; ++j)
                    acc[i][j] = __builtin_amdgcn_mfma_f32_16x16x32_bf16(a[i], b[j], acc[i][j], 0, 0, 0);
            }
            __builtin_amdgcn_s_setprio(0);
        }
    }

    if (STORE) {
        #pragma unroll
        for (int i = 0; i < MT; ++i) {
            #pragma unroll
            for (int j = 0; j < NT; ++j) {
                const int row = ptb + j * 16 + lr;          // point
                const int col = (otb + i) * 16 + lq * 4;    // output dim (4 contiguous)
                if (OUTF32) {
                    *(f32x4*)((float*)outP + row * sOut + col) = acc[i][j];
                } else {
                    f32x4 v = acc[i][j];
                    if (RELU) {
                        v[0] = fmaxf(v[0], 0.0f); v[1] = fmaxf(v[1], 0.0f);
                        v[2] = fmaxf(v[2], 0.0f); v[3] = fmaxf(v[3], 0.0f);
                    }
                    *(bf16x4*)((short*)outP + row * sOut + col) = cvt4(v);
                }
            }
        }
    }
}

// ---- 32x32x16 chunked role-swapped layer (L3, L4) -------------------------
//  A: lane -> A[od = otb*32 + (lane&31)][k = kt*16 + (lane>>5)*8 + e]
//  B: lane -> act[pt = ptb + (lane&31)][k = kt*16 + (lane>>5)*8 + e]
//  D (m74/m101): pt = lane&31, od = (r&3) + 8*(r>>2) + 4*(lane>>5)
// Chunked double-buffer (m97 batch pattern): issue ALL chunk c+1 loads,
// then MFMA chunk c. CH k-tiles per chunk; all buffer indices static.
template<int K, int OT, int MT, int NT, int KTS, int KT0, int CH,
         bool RELU, bool INIT, bool STORE>
__device__ __forceinline__ void mlp_layer32c(f32x16 (&acc)[MT][NT],
                                             const short* __restrict__ act, const int sIn,
                                             short* __restrict__ outP, const int sOut,
                                             const short* __restrict__ pack,
                                             const float* __restrict__ bias,
                                             const int wave, const int lane) {
    constexpr int PTG = 2 / NT;
    constexpr int OG  = OT / MT;
    constexpr int KT  = K / 16;
    constexpr int NC  = KT / CH;         // chunks (KT % CH == 0)
    const int og = wave / PTG;
    if (og >= OG) return;
    const int ptb = (wave % PTG) * (NT * 32);
    const int otb = og * MT;
    const int lr = lane & 31, hi = lane >> 5;

    if (INIT) {
        #pragma unroll
        for (int i = 0; i < MT; ++i) {
            #pragma unroll
            for (int rg = 0; rg < 4; ++rg) {
                f32x4 bv = *(const f32x4*)(bias + (otb + i) * 32 + rg * 8 + hi * 4);
                #pragma unroll
                for (int j = 0; j < NT; ++j) {
                    acc[i][j][rg * 4 + 0] = bv[0];
                    acc[i][j][rg * 4 + 1] = bv[1];
                    acc[i][j][rg * 4 + 2] = bv[2];
                    acc[i][j][rg * 4 + 3] = bv[3];
                }
            }
        }
    }

    const short* ap = pack + ((otb * KTS + KT0) << 9) + (lane << 3);
    const short* bp = act + (ptb + lr) * sIn + hi * 8;

    bf16x8 a[2][CH][MT], b[2][CH][NT];

#define LOADC(B_, C_)                                                           \
    {   _Pragma("unroll")                                                       \
        for (int t = 0; t < CH; ++t) {                                          \
            _Pragma("unroll")                                                   \
            for (int i = 0; i < MT; ++i)                                        \
                a[B_][t][i] = *(const bf16x8*)(ap + ((i * KTS + (C_) * CH + t) << 9)); \
            _Pragma("unroll")                                                   \
            for (int j = 0; j < NT; ++j)                                        \
                b[B_][t][j] = *(const bf16x8*)(bp + j * 32 * sIn + ((C_) * CH + t) * 16); \
        } }

    LOADC(0, 0)
    #pragma unroll
    for (int c = 0; c < NC; ++c) {
        if (c + 1 < NC) LOADC((c + 1) & 1, c + 1)
        __builtin_amdgcn_s_setprio(1);
        #pragma unroll
        for (int t = 0; t < CH; ++t) {
            #pragma unroll
            for (int i = 0; i < MT; ++i) {
                #pragma unroll
                for (int j = 0; j < NT; ++j)
                    acc[i][j] = __builtin_amdgcn_mfma_f32_32x32x16_bf16(
                        a[c & 1][t][i], b[c & 1][t][j], acc[i][j], 0, 0, 0);
            }
        }
        __builtin_amdgcn_s_setprio(0);
    }
#undef LOADC

    if (STORE) {
        #pragma unroll
        for (int i = 0; i < MT; ++i) {
            #pragma unroll
            for (int j = 0; j < NT; ++j) {
                const int row = ptb + j * 32 + lr;
                #pragma unroll
                for (int rg = 0; rg < 4; ++rg) {
                    f32x4 v;
                    v[0] = acc[i][j][rg * 4 + 0]; v[1] = acc[i][j][rg * 4 + 1];
                    v[2] = acc[i][j][rg * 4 + 2]; v[3] = acc[i][j][rg * 4 + 3];
                    if (RELU) {
                        v[0] = fmaxf(v[0], 0.0f); v[1] = fmaxf(v[1], 0.0f);
                        v[2] = fmaxf(v[2], 0.0f); v[3] = fmaxf(v[3], 0.0f);
                    }
                    *(bf16x4*)(outP + row * sOut + (otb + i) * 32 + rg * 8 + hi * 4) = cvt4(v);
                }
            }
        }
    }
}

__global__ __launch_bounds__(512, 4) void gridnet_fused(
    const float* __restrict__ pos, const float* __restrict__ grid_pos,
    const float* __restrict__ w1, const float* __restrict__ b1,
    const float* __restrict__ b2, const float* __restrict__ b3,
    const float* __restrict__ b4, const float* __restrict__ b5,
    const short* __restrict__ ws, float* __restrict__ out) {

    // region1: h2, then h4.   region2: h3a/h3b, then logits (f32).
    // region3: h1, then h5.   Peak LDS = 33792+33792+9216+512 = 77312 B -> 2 blk/CU.
    __shared__ short region1[64 * 264];
    __shared__ short region2[64 * 264];
    __shared__ short region3[64 * 72];
    __shared__ float posS[128];
    float* logitsS = (float*)region2;    // 64*80*4 = 20480 <= 33792

    const int tid  = threadIdx.x;
    const int wave = tid >> 6;
    const int lane = tid & 63;
    const int m0   = blockIdx.x * 64;

    if (tid < 128) posS[tid] = pos[m0 * 2 + tid];
    __syncthreads();

    // ---- layer 1 (2 -> 64), VALU; h1 stored [pt][dim] stride 72 ----
    #pragma unroll
    for (int r = 0; r < 8; ++r) {
        int idx = tid + r * 512;          // 64 pts x 64 dims
        int m = idx >> 6, n = idx & 63;
        float v = fmaf(posS[m * 2 + 0], w1[n], fmaf(posS[m * 2 + 1], w1[64 + n], b1[n]));
        region3[m * 72 + n] = f2bf(fmaxf(v, 0.0f));
    }
    __syncthreads();

    {   // L2: 64 -> 256 (16-shape)
        f32x4 acc[2][4];
        mlp_layer< 64, 16, 2, 4,  2, 0, true, false, true, true, true>(
            acc, region3, 72, region1, 264, ws + P2_OFF, b2, wave, lane);
    }
    __syncthreads();

    {   // L4 accumulator lives across both halves (32-shape, 32 VGPRs)
        f32x16 acc4[2][1];
        {   // L3a: h2 -> h3a (od 0..255), CH=2
            f32x16 acc[2][1];
            mlp_layer32c<256, 8, 2, 1, 16, 0, 2, true, true, true>(
                acc, region1, 264, region2, 264, ws + P3_OFF, b3, wave, lane);
        }
        __syncthreads();
        // L4 part 1: k = 0..255 (h3a), bias-init, no store, CH=2
        mlp_layer32c<256, 8, 2, 1, 32, 0, 2, true, true, false>(
            acc4, region2, 264, region1, 264, ws + P4_OFF, b4, wave, lane);
        __syncthreads();
        {   // L3b: h2 -> h3b (od 256..511); CH=1 (acc4 live, VGPR cap)
            f32x16 acc[2][1];
            mlp_layer32c<256, 8, 2, 1, 16, 0, 1, true, true, true>(
                acc, region1, 264, region2, 264, ws + P3_OFF + (16 * 8 * 512), b3 + 256,
                wave, lane);
        }
        __syncthreads();
        // L4 part 2: k = 256..511 (h3b; weight k-tiles 16..31), store h4, CH=2
        mlp_layer32c<256, 8, 2, 1, 32, 16, 2, true, false, true>(
            acc4, region2, 264, region1, 264, ws + P4_OFF, b4, wave, lane);
    }
    __syncthreads();

    {   // L5: 256 -> 64 (16-shape)
        f32x4 acc[1][2];
        mlp_layer<256,  4, 1, 2,  8, 0, true, false, true, true, true>(
            acc, region1, 264, region3, 72, ws + P5_OFF, b5, wave, lane);
    }
    __syncthreads();

    {   // L6: 64 -> 80 logits (f32, 16-shape)
        f32x4 acc[1][4];
        mlp_layer< 64,  5, 1, 4,  2, 0, false, true, true, true, true>(
            acc, region3, 72, logitsS, 80, ws + P6_OFF,
            (const float*)(ws + B6_OFF), wave, lane);
    }
    __syncthreads();

    // ---- epilogue: softmax(75) + 5x5x3 gather + sigmoid, 8 lanes per point ----
    const int p = tid >> 3;              // point within tile
    const int s = tid & 7;               // sub-lane
    const float p0 = posS[p * 2 + 0], p1 = posS[p * 2 + 1];
    const int tx0 = (int)(p0 / PI_F * 1023.0f);                 // == int(gx), ix = tx0 + dy
    const int ty0 = (int)((p1 + PI_F) / TWO_PI_F * 2047.0f);    // == int(gy), iy = ty0 + dx

    const float* lrow = logitsS + p * 80;
    float lv[10];
    float mx = -1e30f;
    #pragma unroll
    for (int i = 0; i < 10; ++i) {
        int f = s + i * 8;
        float v = (f < 75) ? lrow[f] : -1e30f;
        lv[i] = v;
        mx = fmaxf(mx, v);
    }
    mx = fmaxf(mx, __shfl_xor(mx, 1, 8));
    mx = fmaxf(mx, __shfl_xor(mx, 2, 8));
    mx = fmaxf(mx, __shfl_xor(mx, 4, 8));

    float den = 0.0f, x0 = 0.0f, x1 = 0.0f, x2 = 0.0f;
    #pragma unroll
    for (int i = 0; i < 10; ++i) {
        int f = s + i * 8;
        if (f < 75) {
            float e = __expf(lv[i] - mx);
            den += e;
            int c = f / 25, rr = f % 25, dy = rr / 5, dx = rr % 5;
            float g = grid_pos[((tx0 + dy) * 2052 + (ty0 + dx)) * 3 + c];
            if      (c == 0) x0 += e * g;
            else if (c == 1) x1 += e * g;
            else             x2 += e * g;
        }
    }
    #pragma unroll
    for (int mask = 1; mask < 8; mask <<= 1) {
        den += __shfl_xor(den, mask, 8);
        x0  += __shfl_xor(x0,  mask, 8);
        x1  += __shfl_xor(x1,  mask, 8);
        x2  += __shfl_xor(x2,  mask, 8);
    }
    if (s < 3) {
        float xv = (s == 0) ? x0 : (s == 1 ? x1 : x2);
        xv /= den;
        float sig = 1.0f / (1.0f + __expf(-xv));
        out[(m0 + p) * 3 + s] = (sig > 0.1f) ? sig * 255.0f : 0.0f;
    }
}

extern "C" void kernel_launch(void* const* d_in, const int* in_sizes, int n_in,
                              void* d_out, int out_size, void* d_ws, size_t ws_size,
                              hipStream_t stream) {
    const float* pos      = (const float*)d_in[0];
    const float* grid_pos = (const float*)d_in[1];
    const float* w1 = (const float*)d_in[2];
    const float* b1 = (const float*)d_in[3];
    const float* w2 = (const float*)d_in[4];
    const float* b2 = (const float*)d_in[5];
    const float* w3 = (const float*)d_in[6];
    const float* b3 = (const float*)d_in[7];
    const float* w4 = (const float*)d_in[8];
    const float* b4 = (const float*)d_in[9];
    const float* w5 = (const float*)d_in[10];
    const float* b5 = (const float*)d_in[11];
    const float* w6 = (const float*)d_in[12];
    const float* b6 = (const float*)d_in[13];
    short* ws = (short*)d_ws;
    float* out = (float*)d_out;

    prep_weights<<<(PREP_TOTAL + 255) / 256, 256, 0, stream>>>(w2, w3, w4, w5, w6, b6, ws);
    gridnet_fused<<<262144 / 64, 512, 0, stream>>>(pos, grid_pos, w1, b1, b2, b3, b4, b5, ws, out);
}

// Round 8
// 280.273 us; speedup vs baseline: 1.1560x; 1.0489x over previous
//
#include <hip/hip_runtime.h>

// ---------------------------------------------------------------------------
// GridNet fused forward: MLP (bf16 MFMA) + softmax + 5x5 gather + sigmoid
// B=262144, GS=(1024,2048), NS=5, layers 2-64-256-512-256-64-75
// R5..R11 history: 253 -> 240us. MfmaUtil pinned at 27-29 across THREE
//   schedule attacks (occupancy 1/2/3 blk/CU, rolling depth-4 PF, chunked
//   dbuf batch loads). VGPR=60 in R11: compiler discards prefetch buffers.
//   => latency war unwinnable at source level; the floor is TRAFFIC:
//   A-operand (weights) 1.13MB/block from L2 through per-CU VMEM (~9-18k
//   cyc/slot) + LDS ~10k + MFMA 9.7k (=27% MfmaUtil exactly) ~ wall.
// R12: cut A-traffic 3.5x. M=128 pts/block, PTG=1 on L3/L4/L6 (each weight
//   frag read by ONE wave; its B-frags span all 128 pts, NT=4). A-bytes:
//   17.7 -> 5.1 KB/pt. Cost: MT=1 -> LDS B-reads ~2.4MB/block (LDS pipe
//   ~19k cyc/slot, new co-leader with MFMA 19.4k). 1 blk/CU, VGPR cap 256
//   (launch_bounds(512,2)); worst live = acc3 64 + acc4 64 + bufs ~ 215.
//   Keeps R9 cvt_pk + setprio.
// ---------------------------------------------------------------------------

#define PI_F     3.14159265358979323846f
#define TWO_PI_F 6.28318530717958647692f

typedef __attribute__((ext_vector_type(8))) short bf16x8;   // 8 bf16 = 4 VGPRs
typedef __attribute__((ext_vector_type(4))) short bf16x4;   // 8 B packed
typedef __attribute__((ext_vector_type(4))) float f32x4;    // 16x16 MFMA C/D
typedef __attribute__((ext_vector_type(16))) float f32x16;  // 32x32 MFMA C/D
typedef __attribute__((ext_vector_type(4))) __bf16 bfv4;

__device__ __forceinline__ short f2bf(float f) {            // RNE, 1 instr
    __bf16 b = (__bf16)f;
    return __builtin_bit_cast(short, b);
}
__device__ __forceinline__ bf16x4 cvt4(f32x4 v) {           // 2x v_cvt_pk_bf16_f32
    bfv4 b = __builtin_convertvector(v, bfv4);
    return __builtin_bit_cast(bf16x4, b);
}

// ws layout (shorts). Weights fragment-packed for MFMA A-operand.
// 16-shape layers (L2,L5,L6): frag f = ot*KT + kt (ot 16-wide, kt 32-deep):
//   lane*8+e <-> W[k = kt*32 + (lane>>4)*8 + e][n = ot*16 + (lane&15)]
// 32-shape layers (L3,L4):    frag f = ot*KT + kt (ot 32-wide, kt 16-deep):
//   lane*8+e <-> W[k = kt*16 + (lane>>5)*8 + e][n = ot*32 + (lane&31)]
// L2: 64x256 (KT=2,  16-shape) @ 0       (16384)
// L3: 256x512(KT=16, 32-shape) @ 16384   (131072)
// L4: 512x256(KT=32, 32-shape) @ 147456  (131072)
// L5: 256x64 (KT=8,  16-shape) @ 278528  (16384)
// L6: 64x80  (KT=2,  16-shape) @ 294912  (5120, cols 75..79 zeroed)
// b6pad: 80 f32 @ short-offset 300032
#define P2_OFF 0
#define P3_OFF 16384
#define P4_OFF 147456
#define P5_OFF 278528
#define P6_OFF 294912
#define B6_OFF 300032
#define PREP_W_TOTAL 300032
#define PREP_TOTAL (PREP_W_TOTAL + 80)

__global__ void prep_weights(const float* __restrict__ w2, const float* __restrict__ w3,
                             const float* __restrict__ w4, const float* __restrict__ w5,
                             const float* __restrict__ w6, const float* __restrict__ b6,
                             short* __restrict__ ws) {
    int idx = blockIdx.x * blockDim.x + threadIdx.x;
    if (idx >= PREP_TOTAL) return;
    if (idx >= PREP_W_TOTAL) {                   // padded bias6 as float
        int n = idx - PREP_W_TOTAL;
        ((float*)(ws + B6_OFF))[n] = (n < 75) ? b6[n] : 0.0f;
        return;
    }
    int rel, KT, N;
    bool s32;
    const float* W;
    if (idx < P3_OFF)      { rel = idx - P2_OFF; KT = 2;  N = 256; W = w2; s32 = false; }
    else if (idx < P4_OFF) { rel = idx - P3_OFF; KT = 16; N = 512; W = w3; s32 = true;  }
    else if (idx < P5_OFF) { rel = idx - P4_OFF; KT = 32; N = 256; W = w4; s32 = true;  }
    else if (idx < P6_OFF) { rel = idx - P5_OFF; KT = 8;  N = 64;  W = w5; s32 = false; }
    else                   { rel = idx - P6_OFF; KT = 2;  N = 80;  W = w6; s32 = false; }
    int f = rel >> 9, r = rel & 511, lane = r >> 3, e = r & 7;
    int kt = f % KT, ot = f / KT;
    int n, k;
    if (s32) { n = ot * 32 + (lane & 31); k = kt * 16 + (lane >> 5) * 8 + e; }
    else     { n = ot * 16 + (lane & 15); k = kt * 32 + (lane >> 4) * 8 + e; }
    float v;
    if (N == 80) v = (n < 75) ? w6[k * 75 + n] : 0.0f;   // true row stride 75
    else         v = W[k * N + n];
    ws[idx] = f2bf(v);
}

// ---- 16x16x32 role-swapped layer (L2, L5, L6) -----------------------------
// D[od][pt] = sum_k W^T[od][k] * act[k][pt] (+bias[od])
// PTS: 16-pt tiles in block (M/16). PTG = PTS/NT; OG = ODT/MT.
template<int K, int ODT, int PTS, int MT, int NT, int KTS, int KT0,
         bool RELU, bool OUTF32, bool INIT, bool STORE, bool PF>
__device__ __forceinline__ void mlp_layer(f32x4 (&acc)[MT][NT],
                                          const short* __restrict__ act, const int sIn,
                                          void* __restrict__ outP, const int sOut,
                                          const short* __restrict__ pack,
                                          const float* __restrict__ bias,
                                          const int wave, const int lane) {
    constexpr int PTG = PTS / NT;        // point groups
    constexpr int OG  = ODT / MT;        // od groups
    constexpr int KT  = K / 32;          // k-tiles this pass
    const int og = wave / PTG;
    if (og >= OG) return;
    const int ptb = (wave % PTG) * (NT * 16);
    const int otb = og * MT;
    const int lr = lane & 15, lq = lane >> 4;

    if (INIT) {
        #pragma unroll
        for (int i = 0; i < MT; ++i) {
            f32x4 bv = *(const f32x4*)(bias + (otb + i) * 16 + lq * 4);
            #pragma unroll
            for (int j = 0; j < NT; ++j) acc[i][j] = bv;
        }
    }

    const short* ap = pack + ((otb * KTS + KT0) << 9) + (lane << 3);
    const short* bp = act + (ptb + lr) * sIn + lq * 8;

    if (PF) {
        bf16x8 a[MT], b[NT];
        #pragma unroll
        for (int i = 0; i < MT; ++i) a[i] = *(const bf16x8*)(ap + ((i * KTS) << 9));
        #pragma unroll
        for (int j = 0; j < NT; ++j) b[j] = *(const bf16x8*)(bp + j * 16 * sIn);

        #pragma unroll
        for (int kt = 0; kt < KT - 1; ++kt) {
            bf16x8 a2[MT], b2[NT];
            #pragma unroll
            for (int i = 0; i < MT; ++i) a2[i] = *(const bf16x8*)(ap + ((i * KTS + kt + 1) << 9));
            #pragma unroll
            for (int j = 0; j < NT; ++j) b2[j] = *(const bf16x8*)(bp + j * 16 * sIn + (kt + 1) * 32);
            __builtin_amdgcn_s_setprio(1);
            #pragma unroll
            for (int i = 0; i < MT; ++i) {
                #pragma unroll
                for (int j = 0; j < NT; ++j)
                    acc[i][j] = __builtin_amdgcn_mfma_f32_16x16x32_bf16(a[i], b[j], acc[i][j], 0, 0, 0);
            }
            __builtin_amdgcn_s_setprio(0);
            #pragma unroll
            for (int i = 0; i < MT; ++i) a[i] = a2[i];
            #pragma unroll
            for (int j = 0; j < NT; ++j) b[j] = b2[j];
        }
        __builtin_amdgcn_s_setprio(1);
        #pragma unroll
        for (int i = 0; i < MT; ++i) {
            #pragma unroll
            for (int j = 0; j < NT; ++j)
                acc[i][j] = __builtin_amdgcn_mfma_f32_16x16x32_bf16(a[i], b[j], acc[i][j], 0, 0, 0);
        }
        __builtin_amdgcn_s_setprio(0);
    } else {
        #pragma unroll
        for (int kt = 0; kt < KT; ++kt) {
            bf16x8 a[MT], b[NT];
            #pragma unroll
            for (int i = 0; i < MT; ++i) a[i] = *(const bf16x8*)(ap + ((i * KTS + kt) << 9));
            #pragma unroll
            for (int j = 0; j < NT; ++j) b[j] = *(const bf16x8*)(bp + j * 16 * sIn + kt * 32);
            __builtin_amdgcn_s_setprio(1);
            #pragma unroll
            for (int i = 0; i < MT; ++i) {
                #pragma unroll
                for (int j = 0; j < NT; ++j)
                    acc[i][j] = __builtin_amdgcn_mfma_f32_16x16x32_bf16(a[i], b[j], acc[i][j], 0, 0, 0);
            }
            __builtin_amdgcn_s_setprio(0);
        }
    }

    if (STORE) {
        #pragma unroll
        for (int i = 0; i < MT; ++i) {
            #pragma unroll
            for (int j = 0; j < NT; ++j) {
                const int row = ptb + j * 16 + lr;          // point
                const int col = (otb + i) * 16 + lq * 4;    // output dim (4 contiguous)
                if (OUTF32) {
                    *(f32x4*)((float*)outP + row * sOut + col) = acc[i][j];
                } else {
                    f32x4 v = acc[i][j];
                    if (RELU) {
                        v[0] = fmaxf(v[0], 0.0f); v[1] = fmaxf(v[1], 0.0f);
                        v[2] = fmaxf(v[2], 0.0f); v[3] = fmaxf(v[3], 0.0f);
                    }
                    *(bf16x4*)((short*)outP + row * sOut + col) = cvt4(v);
                }
            }
        }
    }
}

// ---- 32x32x16 chunked role-swapped layer (L3, L4) -------------------------
//  A: lane -> A[od = otb*32 + (lane&31)][k = kt*16 + (lane>>5)*8 + e]
//  B: lane -> act[pt = ptb + (lane&31)][k = kt*16 + (lane>>5)*8 + e]
//  D (m74/m101): pt = lane&31, od = (r&3) + 8*(r>>2) + 4*(lane>>5)
// PTS: 32-pt tiles (M/32). PTG = PTS/NT; OG = OT/MT. CH k-tiles per chunk,
// double-buffered batch loads (all indices static).
template<int K, int OT, int PTS, int MT, int NT, int KTS, int KT0, int CH,
         bool RELU, bool INIT, bool STORE>
__device__ __forceinline__ void mlp_layer32c(f32x16 (&acc)[MT][NT],
                                             const short* __restrict__ act, const int sIn,
                                             short* __restrict__ outP, const int sOut,
                                             const short* __restrict__ pack,
                                             const float* __restrict__ bias,
                                             const int wave, const int lane) {
    constexpr int PTG = PTS / NT;
    constexpr int OG  = OT / MT;
    constexpr int KT  = K / 16;
    constexpr int NC  = KT / CH;         // chunks (KT % CH == 0)
    const int og = wave / PTG;
    if (og >= OG) return;
    const int ptb = (wave % PTG) * (NT * 32);
    const int otb = og * MT;
    const int lr = lane & 31, hi = lane >> 5;

    if (INIT) {
        #pragma unroll
        for (int i = 0; i < MT; ++i) {
            #pragma unroll
            for (int rg = 0; rg < 4; ++rg) {
                f32x4 bv = *(const f32x4*)(bias + (otb + i) * 32 + rg * 8 + hi * 4);
                #pragma unroll
                for (int j = 0; j < NT; ++j) {
                    acc[i][j][rg * 4 + 0] = bv[0];
                    acc[i][j][rg * 4 + 1] = bv[1];
                    acc[i][j][rg * 4 + 2] = bv[2];
                    acc[i][j][rg * 4 + 3] = bv[3];
                }
            }
        }
    }

    const short* ap = pack + ((otb * KTS + KT0) << 9) + (lane << 3);
    const short* bp = act + (ptb + lr) * sIn + hi * 8;

    bf16x8 a[2][CH][MT], b[2][CH][NT];

#define LOADC(B_, C_)                                                           \
    {   _Pragma("unroll")                                                       \
        for (int t = 0; t < CH; ++t) {                                          \
            _Pragma("unroll")                                                   \
            for (int i = 0; i < MT; ++i)                                        \
                a[B_][t][i] = *(const bf16x8*)(ap + ((i * KTS + (C_) * CH + t) << 9)); \
            _Pragma("unroll")                                                   \
            for (int j = 0; j < NT; ++j)                                        \
                b[B_][t][j] = *(const bf16x8*)(bp + j * 32 * sIn + ((C_) * CH + t) * 16); \
        } }

    LOADC(0, 0)
    #pragma unroll
    for (int c = 0; c < NC; ++c) {
        if (c + 1 < NC) LOADC((c + 1) & 1, c + 1)
        __builtin_amdgcn_s_setprio(1);
        #pragma unroll
        for (int t = 0; t < CH; ++t) {
            #pragma unroll
            for (int i = 0; i < MT; ++i) {
                #pragma unroll
                for (int j = 0; j < NT; ++j)
                    acc[i][j] = __builtin_amdgcn_mfma_f32_32x32x16_bf16(
                        a[c & 1][t][i], b[c & 1][t][j], acc[i][j], 0, 0, 0);
            }
        }
        __builtin_amdgcn_s_setprio(0);
    }
#undef LOADC

    if (STORE) {
        #pragma unroll
        for (int i = 0; i < MT; ++i) {
            #pragma unroll
            for (int j = 0; j < NT; ++j) {
                const int row = ptb + j * 32 + lr;
                #pragma unroll
                for (int rg = 0; rg < 4; ++rg) {
                    f32x4 v;
                    v[0] = acc[i][j][rg * 4 + 0]; v[1] = acc[i][j][rg * 4 + 1];
                    v[2] = acc[i][j][rg * 4 + 2]; v[3] = acc[i][j][rg * 4 + 3];
                    if (RELU) {
                        v[0] = fmaxf(v[0], 0.0f); v[1] = fmaxf(v[1], 0.0f);
                        v[2] = fmaxf(v[2], 0.0f); v[3] = fmaxf(v[3], 0.0f);
                    }
                    *(bf16x4*)(outP + row * sOut + (otb + i) * 32 + rg * 8 + hi * 4) = cvt4(v);
                }
            }
        }
    }
}

__global__ __launch_bounds__(512, 2) void gridnet_fused(
    const float* __restrict__ pos, const float* __restrict__ grid_pos,
    const float* __restrict__ w1, const float* __restrict__ b1,
    const float* __restrict__ b2, const float* __restrict__ b3,
    const float* __restrict__ b4, const float* __restrict__ b5,
    const short* __restrict__ ws, float* __restrict__ out) {

    // M=128 pts/block. region1: h2 -> h4 -> logits(f32).
    // region2: h3a -> h3b.  region3: h1 -> h5.
    // LDS = 67584 + 67584 + 18432 + 1024 = 154624 B -> 1 block/CU (8 waves).
    __shared__ short region1[128 * 264];
    __shared__ short region2[128 * 264];
    __shared__ short region3[128 * 72];
    __shared__ float posS[256];
    float* logitsS = (float*)region1;    // 128*80*4 = 40960 <= 67584

    const int tid  = threadIdx.x;
    const int wave = tid >> 6;
    const int lane = tid & 63;
    const int m0   = blockIdx.x * 128;

    if (tid < 256) posS[tid] = pos[m0 * 2 + tid];
    __syncthreads();

    // ---- layer 1 (2 -> 64), VALU; h1 stored [pt][dim] stride 72 ----
    #pragma unroll
    for (int r = 0; r < 16; ++r) {
        int idx = tid + r * 512;          // 128 pts x 64 dims
        int m = idx >> 6, n = idx & 63;
        float v = fmaf(posS[m * 2 + 0], w1[n], fmaf(posS[m * 2 + 1], w1[64 + n], b1[n]));
        region3[m * 72 + n] = f2bf(fmaxf(v, 0.0f));
    }
    __syncthreads();

    {   // L2: 64 -> 256. PTS=8, NT=4 (PTG=2), MT=4 (OG=4). A=64KB. acc 64 VGPR.
        f32x4 acc[4][4];
        mlp_layer< 64, 16, 8, 4, 4,  2, 0, true, false, true, true, true>(
            acc, region3, 72, region1, 264, ws + P2_OFF, b2, wave, lane);
    }
    __syncthreads();

    {   // L3/L4 halves; PTG=1 (each weight frag read by ONE wave, B spans 128 pts).
        // acc4[1][4] = 64 VGPR lives across; acc3[1][4] = 64.
        f32x16 acc4[1][4];
        {   // L3a: h2 -> h3a (od 0..255): OT=8, MT=1, OG=8, CH=2
            f32x16 acc[1][4];
            mlp_layer32c<256, 8, 4, 1, 4, 16, 0, 2, true, true, true>(
                acc, region1, 264, region2, 264, ws + P3_OFF, b3, wave, lane);
        }
        __syncthreads();
        // L4 part 1: k = 0..255 (h3a), bias-init, no store, CH=2
        mlp_layer32c<256, 8, 4, 1, 4, 32, 0, 2, true, true, false>(
            acc4, region2, 264, region1, 264, ws + P4_OFF, b4, wave, lane);
        __syncthreads();
        {   // L3b: h2 -> h3b (od 256..511); CH=1 (acc4 live, cap VGPR)
            f32x16 acc[1][4];
            mlp_layer32c<256, 8, 4, 1, 4, 16, 0, 1, true, true, true>(
                acc, region1, 264, region2, 264, ws + P3_OFF + 65536, b3 + 256,
                wave, lane);
        }
        __syncthreads();
        // L4 part 2: k = 256..511 (weight k-tiles 16..31), store h4, CH=2
        mlp_layer32c<256, 8, 4, 1, 4, 32, 16, 2, true, false, true>(
            acc4, region2, 264, region1, 264, ws + P4_OFF, b4, wave, lane);
    }
    __syncthreads();

    {   // L5: 256 -> 64. PTS=8, NT=4 (PTG=2), MT=1 (OG=4). A=64KB.
        f32x4 acc[1][4];
        mlp_layer<256,  4, 8, 1, 4,  8, 0, true, false, true, true, true>(
            acc, region1, 264, region3, 72, ws + P5_OFF, b5, wave, lane);
    }
    __syncthreads();

    {   // L6: 64 -> 80 logits (f32). PTS=8, NT=8 (PTG=1), MT=1, OG=5 (3 waves idle).
        f32x4 acc[1][8];
        mlp_layer< 64,  5, 8, 1, 8,  2, 0, false, true, true, true, true>(
            acc, region3, 72, logitsS, 80, ws + P6_OFF,
            (const float*)(ws + B6_OFF), wave, lane);
    }
    __syncthreads();

    // ---- epilogue: softmax(75) + 5x5x3 gather + sigmoid, 8 lanes/pt, 2 halves ----
    const int s = tid & 7;               // sub-lane
    #pragma unroll
    for (int half = 0; half < 2; ++half) {
        const int p = (tid >> 3) + half * 64;    // point within tile
        const float p0 = posS[p * 2 + 0], p1 = posS[p * 2 + 1];
        const int tx0 = (int)(p0 / PI_F * 1023.0f);
        const int ty0 = (int)((p1 + PI_F) / TWO_PI_F * 2047.0f);

        const float* lrow = logitsS + p * 80;
        float lv[10];
        float mx = -1e30f;
        #pragma unroll
        for (int i = 0; i < 10; ++i) {
            int f = s + i * 8;
            float v = (f < 75) ? lrow[f] : -1e30f;
            lv[i] = v;
            mx = fmaxf(mx, v);
        }
        mx = fmaxf(mx, __shfl_xor(mx, 1, 8));
        mx = fmaxf(mx, __shfl_xor(mx, 2, 8));
        mx = fmaxf(mx, __shfl_xor(mx, 4, 8));

        float den = 0.0f, x0 = 0.0f, x1 = 0.0f, x2 = 0.0f;
        #pragma unroll
        for (int i = 0; i < 10; ++i) {
            int f = s + i * 8;
            if (f < 75) {
                float e = __expf(lv[i] - mx);
                den += e;
                int c = f / 25, rr = f % 25, dy = rr / 5, dx = rr % 5;
                float g = grid_pos[((tx0 + dy) * 2052 + (ty0 + dx)) * 3 + c];
                if      (c == 0) x0 += e * g;
                else if (c == 1) x1 += e * g;
                else             x2 += e * g;
            }
        }
        #pragma unroll
        for (int mask = 1; mask < 8; mask <<= 1) {
            den += __shfl_xor(den, mask, 8);
            x0  += __shfl_xor(x0,  mask, 8);
            x1  += __shfl_xor(x1,  mask, 8);
            x2  += __shfl_xor(x2,  mask, 8);
        }
        if (s < 3) {
            float xv = (s == 0) ? x0 : (s == 1 ? x1 : x2);
            xv /= den;
            float sig = 1.0f / (1.0f + __expf(-xv));
            out[(m0 + p) * 3 + s] = (sig > 0.1f) ? sig * 255.0f : 0.0f;
        }
    }
}

extern "C" void kernel_launch(void* const* d_in, const int* in_sizes, int n_in,
                              void* d_out, int out_size, void* d_ws, size_t ws_size,
                              hipStream_t stream) {
    const float* pos      = (const float*)d_in[0];
    const float* grid_pos = (const float*)d_in[1];
    const float* w1 = (const float*)d_in[2];
    const float* b1 = (const float*)d_in[3];
    const float* w2 = (const float*)d_in[4];
    const float* b2 = (const float*)d_in[5];
    const float* w3 = (const float*)d_in[6];
    const float* b3 = (const float*)d_in[7];
    const float* w4 = (const float*)d_in[8];
    const float* b4 = (const float*)d_in[9];
    const float* w5 = (const float*)d_in[10];
    const float* b5 = (const float*)d_in[11];
    const float* w6 = (const float*)d_in[12];
    const float* b6 = (const float*)d_in[13];
    short* ws = (short*)d_ws;
    float* out = (float*)d_out;

    prep_weights<<<(PREP_TOTAL + 255) / 256, 256, 0, stream>>>(w2, w3, w4, w5, w6, b6, ws);
    gridnet_fused<<<262144 / 128, 512, 0, stream>>>(pos, grid_pos, w1, b1, b2, b3, b4, b5, ws, out);
}